// Round 1
// 471.576 us; speedup vs baseline: 1.0008x; 1.0008x over previous
//
#include <hip/hip_runtime.h>

typedef unsigned int uint;
typedef unsigned short ushort;

#define NN 1000000
#define KSZ 9
#define CH 16
#define KTOT 144          // KSZ*CH
#define NBLK 1024
#define TILES64 15625     // NN / 64

typedef float f32x4 __attribute__((ext_vector_type(4)));
typedef short s16x8 __attribute__((ext_vector_type(8)));

__device__ __forceinline__ float bf2f(ushort v) { return __uint_as_float(((uint)v) << 16); }
__device__ __forceinline__ ushort f2bf(float f) {
  uint u = __float_as_uint(f);
  return (ushort)((u + 0x7fffu + ((u >> 16) & 1u)) >> 16);   // RNE
}
__device__ __forceinline__ float leaky(float x) { return x >= 0.f ? x : 0.2f * x; }

// ---------------------------------------------------------------------------
// Pre-pass: data fp32 -> bf16 copy. conv1 rounded to bf16 during its gather
// anyway (MFMA inputs are bf16), so this is bit-identical math; it halves
// conv1's gathered line footprint (500K -> 250K 128B lines) which raises the
// per-XCD L2 hit fraction and lowers average TCP fill latency (the gather is
// MSHR*latency bound at ~12.2 cy/fill/CU).
// ---------------------------------------------------------------------------
__global__ __launch_bounds__(256)
void k_cast(const float* __restrict__ in, ushort* __restrict__ out) {
  size_t i0 = ((size_t)blockIdx.x * 256 + (size_t)threadIdx.x) * 8;
  if (i0 >= (size_t)NN * CH) return;
  float4 a = *(const float4*)(in + i0);
  float4 b = *(const float4*)(in + i0 + 4);
  float e[8] = {a.x, a.y, a.z, a.w, b.x, b.y, b.z, b.w};
  uint pk[4];
#pragma unroll
  for (int p = 0; p < 4; ++p)
    pk[p] = (uint)f2bf(e[2*p]) | ((uint)f2bf(e[2*p+1]) << 16);
  *(uint4*)(out + i0) = *(uint4*)pk;
}

// ---------------------------------------------------------------------------
// Direct-to-fragment gather conv. One wave owns 16 nodes. The MFMA
// (16x16x32 bf16, K=144 pad 160) A-fragment for lane (m=lane&15, q=lane>>4)
// at K-step t is src row ind[(base+m)*9 + j], j = 2t+(q>>1), channels
// (q&1)*8..+7  -> a single contiguous 16B load. The q-pair's two halves
// coalesce into one 32B line request: exactly 1 TCP request per gathered row
// (was 4x16B for fp32 rows), zero LDS tile, zero bank conflicts.
// Loads use sc0 (L1-bypass; reuse in 32KB L1 is ~0, served from L2).
// t=4 covers j=8 (q<2) and the K-pad (q>=2): padded lanes re-load j=8
// (merges with the q<2 request, no extra traffic) and zero the fragment;
// bfrag k>=144 is also zero.
// BN=false (conv1): src = pre-rounded bf16 data, + bias.
// BN=true  (conv2): src = out1 raw bf16; BN1 scale/shift derived per-block
// from the atomic accumulator, then BN1+leaky applied in-register.
// ---------------------------------------------------------------------------
template<bool BN>
__global__ __launch_bounds__(256)
void k_conv(const ushort* __restrict__ src, const int* __restrict__ ind,
            const float* __restrict__ w, const float* __restrict__ bias,
            const float* __restrict__ statsIn, const float* __restrict__ gamma,
            const float* __restrict__ beta,
            ushort* __restrict__ outv, float* __restrict__ accumOut) {
  const int lane = threadIdx.x & 63;
  const int wid  = threadIdx.x >> 6;
  const int o = lane & 15;     // B/D column (out channel); ALSO A row (node) for loads
  const int q = lane >> 4;
  const int qh = q >> 1;
  const int ch0 = (q & 1) * 8; // which 8-channel half of the row this lane loads

  __shared__ int   idxs[4][160];   // wave-private staged indices (144 used)
  __shared__ float red[4][32];
  __shared__ float dsc[16], dsh[16];

  // B fragments: B[k][o] = w[c*144 + o*9 + j], k = j*16 + c; lane holds k = 32t + 8q + i
  s16x8 bfrag[5];
#pragma unroll
  for (int t = 0; t < 5; ++t) {
#pragma unroll
    for (int i = 0; i < 8; ++i) {
      int k = t * 32 + q * 8 + i;
      ushort wv = 0;
      if (k < KTOT) { int j = k >> 4, c = k & 15; wv = f2bf(w[(c * CH + o) * KSZ + j]); }
      bfrag[t][i] = (short)wv;
    }
  }

  float bo = 0.f;
  float sc8[8], sh8[8];
  if constexpr (BN) {
    // derive BN1 scale/shift per block (replaces the single-block finalize kernel)
    if (threadIdx.x < 16) {
      int c = threadIdx.x;
      float s = statsIn[c], sq = statsIn[16 + c];
      float mean = s * (1.0f / NN);
      float var  = sq * (1.0f / NN) - mean * mean;
      float scale = gamma[c] * rsqrtf(var + 1e-5f);
      dsc[c] = scale; dsh[c] = beta[c] - mean * scale;
    }
    __syncthreads();
#pragma unroll
    for (int i = 0; i < 8; ++i) { sc8[i] = dsc[ch0 + i]; sh8[i] = dsh[ch0 + i]; }
  } else {
    bo = bias[o];
  }

  int* idxw = idxs[wid];
  float wsum = 0.f, wsq = 0.f;

  for (int g = blockIdx.x; g < TILES64; g += NBLK) {
    const int base  = g * 64 + wid * 16;
    const int base9 = base * 9;

    // stage this wave's 144 indices (contiguous, coalesced). Wave-private:
    // intra-wave DS ordering (write->read) is compiler/lgkmcnt enforced.
    {
      int r = lane;            idxw[r] = ind[base9 + r];
      r = lane + 64;           idxw[r] = ind[base9 + r];
      r = lane + 128; if (r < KTOT) idxw[r] = ind[base9 + r];
    }

    // per-lane neighbor indices: j = 2t+qh for t<4; j=8 for t=4 (pad lanes duplicate)
    int i0 = idxw[o * KSZ + (0 + qh)];
    int i1 = idxw[o * KSZ + (2 + qh)];
    int i2 = idxw[o * KSZ + (4 + qh)];
    int i3 = idxw[o * KSZ + (6 + qh)];
    int i4 = idxw[o * KSZ + 8];

    const ushort* p0 = src + (size_t)i0 * CH + ch0;
    const ushort* p1 = src + (size_t)i1 * CH + ch0;
    const ushort* p2 = src + (size_t)i2 * CH + ch0;
    const ushort* p3 = src + (size_t)i3 * CH + ch0;
    const ushort* p4 = src + (size_t)i4 * CH + ch0;

    s16x8 ld0, ld1, ld2, ld3, ld4;
    asm volatile("global_load_dwordx4 %0, %1, off sc0" : "=&v"(ld0) : "v"(p0) : "memory");
    asm volatile("global_load_dwordx4 %0, %1, off sc0" : "=&v"(ld1) : "v"(p1) : "memory");
    asm volatile("global_load_dwordx4 %0, %1, off sc0" : "=&v"(ld2) : "v"(p2) : "memory");
    asm volatile("global_load_dwordx4 %0, %1, off sc0" : "=&v"(ld3) : "v"(p3) : "memory");
    asm volatile("global_load_dwordx4 %0, %1, off sc0" : "=&v"(ld4) : "v"(p4) : "memory");
    asm volatile("s_waitcnt vmcnt(0)" ::: "memory");
    __builtin_amdgcn_sched_barrier(0);   // keep consumers below the waitcnt (rule 18)

    s16x8 a0, a1, a2, a3, a4;
    if constexpr (BN) {
      // h = leaky(scale1*x + shift1), back to bf16 (same rounding as before)
      auto xf = [&](s16x8 v) -> s16x8 {
        s16x8 r;
#pragma unroll
        for (int i = 0; i < 8; ++i) {
          float x = bf2f((ushort)v[i]);
          r[i] = (short)f2bf(leaky(sc8[i] * x + sh8[i]));
        }
        return r;
      };
      a0 = xf(ld0); a1 = xf(ld1); a2 = xf(ld2); a3 = xf(ld3); a4 = xf(ld4);
    } else {
      a0 = ld0; a1 = ld1; a2 = ld2; a3 = ld3; a4 = ld4;
    }
    if (qh) { s16x8 z = {0,0,0,0,0,0,0,0}; a4 = z; }   // K-pad lanes (k>=144)

    f32x4 acc = {0.f, 0.f, 0.f, 0.f};
    acc = __builtin_amdgcn_mfma_f32_16x16x32_bf16(a0, bfrag[0], acc, 0, 0, 0);
    acc = __builtin_amdgcn_mfma_f32_16x16x32_bf16(a1, bfrag[1], acc, 0, 0, 0);
    acc = __builtin_amdgcn_mfma_f32_16x16x32_bf16(a2, bfrag[2], acc, 0, 0, 0);
    acc = __builtin_amdgcn_mfma_f32_16x16x32_bf16(a3, bfrag[3], acc, 0, 0, 0);
    acc = __builtin_amdgcn_mfma_f32_16x16x32_bf16(a4, bfrag[4], acc, 0, 0, 0);

    // D[m][o]: m = q*4+r (node within tile), o = lane&15 (channel)
#pragma unroll
    for (int r = 0; r < 4; ++r) {
      float v = acc[r] + bo;
      ushort hv = f2bf(v);
      outv[(size_t)(base + q * 4 + r) * CH + o] = hv;
      float vr = bf2f(hv);     // stats on the ROUNDED value (matches stored tensor)
      wsum += vr;
      wsq  += vr * vr;
    }
  }

  // per-channel reduce: lanes o, o+16, o+32, o+48 -> block -> global atomic
  wsum += __shfl_xor(wsum, 16);  wsum += __shfl_xor(wsum, 32);
  wsq  += __shfl_xor(wsq, 16);   wsq  += __shfl_xor(wsq, 32);
  if (lane < 16) { red[wid][lane] = wsum; red[wid][16 + lane] = wsq; }
  __syncthreads();
  if (threadIdx.x < 32) {
    float s = red[0][threadIdx.x] + red[1][threadIdx.x] + red[2][threadIdx.x] + red[3][threadIdx.x];
    atomicAdd(&accumOut[threadIdx.x], s);   // [0..15]=sum, [16..31]=sumsq
  }
}

// out = leaky(scale2*out2 + shift2 + data), fp32 out. Derives BN2 scale/shift
// per block from the atomic accumulator (replaces second finalize kernel).
__global__ __launch_bounds__(256)
void k_final(const ushort* __restrict__ o2, const float* __restrict__ data,
             const float* __restrict__ statsIn, const float* __restrict__ gamma,
             const float* __restrict__ beta, float* __restrict__ out) {
  __shared__ float dsc[16], dsh[16];
  if (threadIdx.x < 16) {
    int c = threadIdx.x;
    float s = statsIn[c], sq = statsIn[16 + c];
    float mean = s * (1.0f / NN);
    float var  = sq * (1.0f / NN) - mean * mean;
    float scale = gamma[c] * rsqrtf(var + 1e-5f);
    dsc[c] = scale; dsh[c] = beta[c] - mean * scale;
  }
  __syncthreads();
  size_t t = (size_t)blockIdx.x * 256 + threadIdx.x;
  size_t i0 = t * 8;
  if (i0 >= (size_t)NN * CH) return;
  int coff = (int)(i0 & 15);
  float sc[8], sh[8];
#pragma unroll
  for (int p = 0; p < 8; ++p) { sc[p] = dsc[coff + p]; sh[p] = dsh[coff + p]; }
  uint4 a = *(const uint4*)(o2 + i0);
  float4 d0 = *(const float4*)(data + i0);
  float4 d1 = *(const float4*)(data + i0 + 4);
  uint ua[4] = {a.x, a.y, a.z, a.w};
  float dd[8] = {d0.x, d0.y, d0.z, d0.w, d1.x, d1.y, d1.z, d1.w};
  float y[8];
#pragma unroll
  for (int p = 0; p < 4; ++p) {
    float x0 = __uint_as_float(ua[p] << 16);
    float x1 = __uint_as_float(ua[p] & 0xffff0000u);
    y[2*p]   = leaky(sc[2*p]   * x0 + sh[2*p]   + dd[2*p]);
    y[2*p+1] = leaky(sc[2*p+1] * x1 + sh[2*p+1] + dd[2*p+1]);
  }
  float4 r0 = {y[0], y[1], y[2], y[3]};
  float4 r1 = {y[4], y[5], y[6], y[7]};
  *(float4*)(out + i0) = r0;
  *(float4*)(out + i0 + 4) = r1;
}

extern "C" void kernel_launch(void* const* d_in, const int* in_sizes, int n_in,
                              void* d_out, int out_size, void* d_ws, size_t ws_size,
                              hipStream_t stream) {
  const float* data   = (const float*)d_in[0];
  const int*   ind    = (const int*)d_in[1];
  const float* w1     = (const float*)d_in[2];
  const float* b1     = (const float*)d_in[3];
  const float* gamma1 = (const float*)d_in[4];
  const float* beta1  = (const float*)d_in[5];
  const float* w2     = (const float*)d_in[6];
  const float* gamma2 = (const float*)d_in[7];
  const float* beta2  = (const float*)d_in[8];
  float* out = (float*)d_out;

  // d_out (64MB fp32) doubles as scratch until k_final overwrites:
  //   [0,32MB)   = out1 bf16 (pre-BN1 raw)
  //   [32,64MB)  = dataB bf16 (pre-rounded data; dead after conv1)
  ushort* out1  = (ushort*)d_out;
  ushort* dataB = out1 + (size_t)NN * CH;
  // ws: accum1[32] | accum2[32] | out2 bf16 (32MB)
  float*  accum1 = (float*)d_ws;
  float*  accum2 = accum1 + 32;
  ushort* out2   = (ushort*)((char*)d_ws + 256);

  hipMemsetAsync(d_ws, 0, 256, stream);   // zero both stat accumulators

  hipLaunchKernelGGL(k_cast, dim3((NN * CH / 8 + 255) / 256), dim3(256), 0, stream,
                     data, dataB);
  // conv1: dataB (bf16) -> out1 (bf16 pre-BN) + atomic stats
  hipLaunchKernelGGL((k_conv<false>), dim3(NBLK), dim3(256), 0, stream,
                     dataB, ind, w1, b1,
                     (const float*)nullptr, (const float*)nullptr, (const float*)nullptr,
                     out1, accum1);
  // conv2: gather out1, BN1+leaky in-register -> out2 (bf16 pre-BN) + atomic stats
  hipLaunchKernelGGL((k_conv<true>), dim3(NBLK), dim3(256), 0, stream,
                     out1, ind, w2, (const float*)nullptr,
                     accum1, gamma1, beta1,
                     out2, accum2);
  // residual + BN2 + leaky -> d_out (scratch regions dead)
  hipLaunchKernelGGL(k_final, dim3((NN * CH / 8 + 255) / 256), dim3(256), 0, stream,
                     out2, data, accum2, gamma2, beta2, out);
}